// Round 1
// baseline (83.185 us; speedup 1.0000x reference)
//
#include <hip/hip_runtime.h>

// BCMSELoss: scalar = mean((out_full - tgt_full)^2) + sum(|floor(o_ang)|)/B
// where columns 1,2 get angular wrap treatment, column 0 is plain MSE.
// Memory-bound streaming reduction: 201 MB read -> ~32 us HBM floor.

constexpr int BLOCK = 256;
constexpr int GRID  = 2048;   // ~8 blocks/CU worth of waves; grid-stride the rest

__global__ __launch_bounds__(BLOCK) void bcmse_main(
    const float* __restrict__ outs,
    const float* __restrict__ tgts,
    long long n,                      // total elements = B*3
    double* __restrict__ acc)         // acc[0]=sum_sq, acc[1]=sum_pen
{
    const long long n4 = n >> 2;
    const long long stride = (long long)gridDim.x * BLOCK;

    float sq = 0.f, pen = 0.f;

    for (long long i = (long long)blockIdx.x * BLOCK + threadIdx.x; i < n4; i += stride) {
        const float4 o = reinterpret_cast<const float4*>(outs)[i];
        const float4 t = reinterpret_cast<const float4*>(tgts)[i];
        float ov[4] = {o.x, o.y, o.z, o.w};
        float tv[4] = {t.x, t.y, t.z, t.w};
        int c = (int)((i * 4) % 3);   // column of element 4*i
        #pragma unroll
        for (int j = 0; j < 4; ++j) {
            const float oo = ov[j];
            const float tt = tv[j];
            if (c == 0) {
                const float d = oo - tt;
                sq = fmaf(d, d, sq);
            } else {
                const float fl = floorf(oo);
                pen += fabsf(fl);
                const float ow = oo - fl;                       // mod(o, 1.0)
                const float ts = (fabsf(ow - tt) > 0.5f)
                                   ? (tt + ((tt < ow) ? 1.f : -1.f))
                                   : tt;
                const float d = ow - ts;
                sq = fmaf(d, d, sq);
            }
            c = (c == 2) ? 0 : c + 1;
        }
    }

    // Tail (n not divisible by 4) — handled by a single thread; <=3 elements.
    if (blockIdx.x == 0 && threadIdx.x == 0) {
        for (long long e = n4 * 4; e < n; ++e) {
            const float oo = outs[e];
            const float tt = tgts[e];
            const int c = (int)(e % 3);
            if (c == 0) {
                const float d = oo - tt;
                sq = fmaf(d, d, sq);
            } else {
                const float fl = floorf(oo);
                pen += fabsf(fl);
                const float ow = oo - fl;
                const float ts = (fabsf(ow - tt) > 0.5f)
                                   ? (tt + ((tt < ow) ? 1.f : -1.f))
                                   : tt;
                const float d = ow - ts;
                sq = fmaf(d, d, sq);
            }
        }
    }

    // Wave-64 butterfly reduce
    #pragma unroll
    for (int off = 32; off > 0; off >>= 1) {
        sq  += __shfl_down(sq,  off, 64);
        pen += __shfl_down(pen, off, 64);
    }

    __shared__ float s_sq[BLOCK / 64], s_pen[BLOCK / 64];
    const int lane = threadIdx.x & 63;
    const int wave = threadIdx.x >> 6;
    if (lane == 0) { s_sq[wave] = sq; s_pen[wave] = pen; }
    __syncthreads();

    if (threadIdx.x == 0) {
        float bsq = 0.f, bpen = 0.f;
        #pragma unroll
        for (int w = 0; w < BLOCK / 64; ++w) { bsq += s_sq[w]; bpen += s_pen[w]; }
        atomicAdd(acc + 0, (double)bsq);
        atomicAdd(acc + 1, (double)bpen);
    }
}

__global__ void bcmse_final(const double* __restrict__ acc,
                            float* __restrict__ out,
                            double invN, double invB)
{
    out[0] = (float)(acc[0] * invN + acc[1] * invB);
}

extern "C" void kernel_launch(void* const* d_in, const int* in_sizes, int n_in,
                              void* d_out, int out_size, void* d_ws, size_t ws_size,
                              hipStream_t stream) {
    const float* outs = (const float*)d_in[0];
    const float* tgts = (const float*)d_in[1];
    float* out = (float*)d_out;
    double* acc = (double*)d_ws;

    const long long n = (long long)in_sizes[0];   // B*3
    const double invN = 1.0 / (double)n;          // mse divisor = B*3
    const double invB = 3.0 / (double)n;          // penalty divisor = B

    // d_ws is poisoned once and never re-poisoned between replays: zero it
    // every launch (capture-safe).
    hipMemsetAsync(acc, 0, 2 * sizeof(double), stream);

    bcmse_main<<<GRID, BLOCK, 0, stream>>>(outs, tgts, n, acc);
    bcmse_final<<<1, 1, 0, stream>>>(acc, out, invN, invB);
}

// Round 2
// 44.343 us; speedup vs baseline: 1.8759x; 1.8759x over previous
//
#include <hip/hip_runtime.h>

// BCMSELoss: scalar = mean((out_full - tgt_full)^2) + sum(|floor(o_ang)|)/B
// cols 1,2 angular-wrapped, col 0 plain MSE. Memory-bound: 201 MB read.
//
// R1 lesson: grid-stride loop compiled to 16 VGPRs -> 1 load-pair in flight
// -> latency-bound at 950 GB/s. Fix: one-shot grid, 6 independent float4
// loads per thread, no atomics (block partials -> ws -> 1-block reduce).

constexpr int BLOCK = 256;
constexpr int F4_PER_THREAD = 3;                    // 12 floats = 4 rows
constexpr int F4_PER_BLOCK = BLOCK * F4_PER_THREAD; // 768

__device__ inline void elem(float oo, float tt, bool ang, float& sq, float& pen) {
    const float fl = floorf(oo);
    const float ow = oo - fl;                       // mod(o, 1.0)
    const float shift = (tt < ow) ? 1.0f : -1.0f;
    const float ts = (fabsf(ow - tt) > 0.5f) ? (tt + shift) : tt;
    const float da = ow - ts;
    const float dl = oo - tt;
    const float d = ang ? da : dl;
    sq = fmaf(d, d, sq);
    pen += ang ? fabsf(fl) : 0.0f;
}

__device__ inline void proc4(const float4 o, const float4 t, int im,
                             float& sq, float& pen) {
    // element e = 4*i + j; since 4 == 1 (mod 3), e%3 == (i+j)%3; im = i%3
    elem(o.x, t.x, im != 0, sq, pen);
    int c1 = (im == 2) ? 0 : im + 1;
    elem(o.y, t.y, c1 != 0, sq, pen);
    int c2 = (c1 == 2) ? 0 : c1 + 1;
    elem(o.z, t.z, c2 != 0, sq, pen);
    int c3 = (c2 == 2) ? 0 : c2 + 1;
    elem(o.w, t.w, c3 != 0, sq, pen);
}

__global__ __launch_bounds__(BLOCK) void bcmse_partial(
    const float* __restrict__ outs,
    const float* __restrict__ tgts,
    long long n,                      // total elements = B*3
    float2* __restrict__ partials)    // one per block
{
    const long long n4 = n >> 2;
    const long long i0 = (long long)blockIdx.x * F4_PER_BLOCK + threadIdx.x;
    const long long i1 = i0 + BLOCK;
    const long long i2 = i0 + 2 * BLOCK;
    const bool g0 = i0 < n4, g1 = i1 < n4, g2 = i2 < n4;
    const long long j0 = g0 ? i0 : 0;
    const long long j1 = g1 ? i1 : 0;
    const long long j2 = g2 ? i2 : 0;

    const float4* __restrict__ o4 = reinterpret_cast<const float4*>(outs);
    const float4* __restrict__ t4 = reinterpret_cast<const float4*>(tgts);

    // six independent loads -> max MLP
    const float4 oa = o4[j0], ob = o4[j1], oc = o4[j2];
    const float4 ta = t4[j0], tb = t4[j1], tc = t4[j2];

    float sq = 0.f, pen = 0.f;
    {
        float s = 0.f, p = 0.f;
        proc4(oa, ta, (int)(j0 % 3), s, p);
        if (g0) { sq += s; pen += p; }
    }
    {
        float s = 0.f, p = 0.f;
        proc4(ob, tb, (int)(j1 % 3), s, p);
        if (g1) { sq += s; pen += p; }
    }
    {
        float s = 0.f, p = 0.f;
        proc4(oc, tc, (int)(j2 % 3), s, p);
        if (g2) { sq += s; pen += p; }
    }

    // scalar tail (n % 4 != 0) — never fires for n = B*3 = 25165824
    if (blockIdx.x == 0 && threadIdx.x == 0) {
        for (long long e = n4 * 4; e < n; ++e) {
            elem(outs[e], tgts[e], (e % 3) != 0, sq, pen);
        }
    }

    // wave-64 reduce
    #pragma unroll
    for (int off = 32; off > 0; off >>= 1) {
        sq  += __shfl_down(sq,  off, 64);
        pen += __shfl_down(pen, off, 64);
    }

    __shared__ float s_sq[BLOCK / 64], s_pen[BLOCK / 64];
    const int lane = threadIdx.x & 63;
    const int wave = threadIdx.x >> 6;
    if (lane == 0) { s_sq[wave] = sq; s_pen[wave] = pen; }
    __syncthreads();

    if (threadIdx.x == 0) {
        float bsq = 0.f, bpen = 0.f;
        #pragma unroll
        for (int w = 0; w < BLOCK / 64; ++w) { bsq += s_sq[w]; bpen += s_pen[w]; }
        partials[blockIdx.x] = make_float2(bsq, bpen);
    }
}

__global__ __launch_bounds__(BLOCK) void bcmse_reduce(
    const float2* __restrict__ partials, int nblocks,
    float* __restrict__ out, double invN, double invB)
{
    double dsq = 0.0, dpen = 0.0;
    for (int k = threadIdx.x; k < nblocks; k += BLOCK) {
        const float2 p = partials[k];
        dsq  += (double)p.x;
        dpen += (double)p.y;
    }
    #pragma unroll
    for (int off = 32; off > 0; off >>= 1) {
        dsq  += __shfl_down(dsq,  off, 64);
        dpen += __shfl_down(dpen, off, 64);
    }
    __shared__ double r_sq[BLOCK / 64], r_pen[BLOCK / 64];
    const int lane = threadIdx.x & 63;
    const int wave = threadIdx.x >> 6;
    if (lane == 0) { r_sq[wave] = dsq; r_pen[wave] = dpen; }
    __syncthreads();
    if (threadIdx.x == 0) {
        double fsq = 0.0, fpen = 0.0;
        #pragma unroll
        for (int w = 0; w < BLOCK / 64; ++w) { fsq += r_sq[w]; fpen += r_pen[w]; }
        out[0] = (float)(fsq * invN + fpen * invB);
    }
}

extern "C" void kernel_launch(void* const* d_in, const int* in_sizes, int n_in,
                              void* d_out, int out_size, void* d_ws, size_t ws_size,
                              hipStream_t stream) {
    const float* outs = (const float*)d_in[0];
    const float* tgts = (const float*)d_in[1];
    float* out = (float*)d_out;
    float2* partials = (float2*)d_ws;

    const long long n = (long long)in_sizes[0];        // B*3
    const long long n4 = n >> 2;
    const int nblocks = (int)((n4 + F4_PER_BLOCK - 1) / F4_PER_BLOCK); // 8192
    const double invN = 1.0 / (double)n;               // mse divisor = B*3
    const double invB = 3.0 / (double)n;               // penalty divisor = B

    // partials[0..nblocks) are fully overwritten each launch -> no memset
    bcmse_partial<<<nblocks, BLOCK, 0, stream>>>(outs, tgts, n, partials);
    bcmse_reduce<<<1, BLOCK, 0, stream>>>(partials, nblocks, out, invN, invB);
}

// Round 3
// 38.832 us; speedup vs baseline: 2.1422x; 1.1419x over previous
//
#include <hip/hip_runtime.h>

// BCMSELoss: scalar = mean((out_full - tgt_full)^2) + sum(|floor(o_ang)|)/B
// cols 1,2 angular-wrapped, col 0 plain MSE. Memory-bound: 201 MB read.
//
// R1: grid-stride @16 VGPR -> latency-bound, 950 GB/s.
// R2: 3 f4-pairs/thread one-shot -> 4.5 TB/s.
// R3: 8 f4-pairs/thread (256 B in flight), grid 3072 (exact fit, 12/CU),
//     reduce shrinks 8192->3072 partials.

constexpr int BLOCK = 256;
constexpr int F4T = 8;                      // float4-pairs per thread
constexpr int F4_PER_BLOCK = BLOCK * F4T;   // 2048

__device__ inline void elem(float oo, float tt, bool ang, float& sq, float& pen) {
    const float fl = floorf(oo);
    const float ow = oo - fl;                       // mod(o, 1.0)
    const float shift = (tt < ow) ? 1.0f : -1.0f;
    const float ts = (fabsf(ow - tt) > 0.5f) ? (tt + shift) : tt;
    const float da = ow - ts;
    const float dl = oo - tt;
    const float d = ang ? da : dl;
    sq = fmaf(d, d, sq);
    pen += ang ? fabsf(fl) : 0.0f;
}

__device__ inline void proc4(const float4 o, const float4 t, int im,
                             float& sq, float& pen) {
    // element e = 4*i + j; 4 == 1 (mod 3) so e%3 == (i+j)%3; im = i%3
    elem(o.x, t.x, im != 0, sq, pen);
    const int c1 = (im == 2) ? 0 : im + 1;
    elem(o.y, t.y, c1 != 0, sq, pen);
    const int c2 = (c1 == 2) ? 0 : c1 + 1;
    elem(o.z, t.z, c2 != 0, sq, pen);
    const int c3 = (c2 == 2) ? 0 : c2 + 1;
    elem(o.w, t.w, c3 != 0, sq, pen);
}

__global__ __launch_bounds__(BLOCK) void bcmse_partial(
    const float* __restrict__ outs,
    const float* __restrict__ tgts,
    long long n,                      // total elements = B*3
    float2* __restrict__ partials)    // one per block
{
    const long long n4 = n >> 2;
    const long long base = (long long)blockIdx.x * F4_PER_BLOCK + threadIdx.x;

    const float4* __restrict__ o4 = reinterpret_cast<const float4*>(outs);
    const float4* __restrict__ t4 = reinterpret_cast<const float4*>(tgts);

    // gather indices + guards
    long long idx[F4T];
    bool g[F4T];
    #pragma unroll
    for (int k = 0; k < F4T; ++k) {
        const long long i = base + (long long)k * BLOCK;
        g[k] = i < n4;
        idx[k] = g[k] ? i : 0;
    }

    // issue all 16 loads before any wait -> max MLP
    float4 ov[F4T], tv[F4T];
    #pragma unroll
    for (int k = 0; k < F4T; ++k) ov[k] = o4[idx[k]];
    #pragma unroll
    for (int k = 0; k < F4T; ++k) tv[k] = t4[idx[k]];

    // BLOCK=256, 256%3==1 -> i%3 advances by 1 per chunk
    int im = (int)(base % 3);

    float sq = 0.f, pen = 0.f;
    #pragma unroll
    for (int k = 0; k < F4T; ++k) {
        float s = 0.f, p = 0.f;
        proc4(ov[k], tv[k], im, s, p);
        if (g[k]) { sq += s; pen += p; }
        im = (im == 2) ? 0 : im + 1;
    }

    // scalar tail (n % 4 != 0) — never fires for n = 25165824
    if (blockIdx.x == 0 && threadIdx.x == 0) {
        for (long long e = n4 * 4; e < n; ++e) {
            elem(outs[e], tgts[e], (e % 3) != 0, sq, pen);
        }
    }

    // wave-64 reduce
    #pragma unroll
    for (int off = 32; off > 0; off >>= 1) {
        sq  += __shfl_down(sq,  off, 64);
        pen += __shfl_down(pen, off, 64);
    }

    __shared__ float s_sq[BLOCK / 64], s_pen[BLOCK / 64];
    const int lane = threadIdx.x & 63;
    const int wave = threadIdx.x >> 6;
    if (lane == 0) { s_sq[wave] = sq; s_pen[wave] = pen; }
    __syncthreads();

    if (threadIdx.x == 0) {
        float bsq = 0.f, bpen = 0.f;
        #pragma unroll
        for (int w = 0; w < BLOCK / 64; ++w) { bsq += s_sq[w]; bpen += s_pen[w]; }
        partials[blockIdx.x] = make_float2(bsq, bpen);
    }
}

__global__ __launch_bounds__(BLOCK) void bcmse_reduce(
    const float2* __restrict__ partials, int nblocks,
    float* __restrict__ out, double invN, double invB)
{
    double dsq = 0.0, dpen = 0.0;
    for (int k = threadIdx.x; k < nblocks; k += BLOCK) {
        const float2 p = partials[k];
        dsq  += (double)p.x;
        dpen += (double)p.y;
    }
    #pragma unroll
    for (int off = 32; off > 0; off >>= 1) {
        dsq  += __shfl_down(dsq,  off, 64);
        dpen += __shfl_down(dpen, off, 64);
    }
    __shared__ double r_sq[BLOCK / 64], r_pen[BLOCK / 64];
    const int lane = threadIdx.x & 63;
    const int wave = threadIdx.x >> 6;
    if (lane == 0) { r_sq[wave] = dsq; r_pen[wave] = dpen; }
    __syncthreads();
    if (threadIdx.x == 0) {
        double fsq = 0.0, fpen = 0.0;
        #pragma unroll
        for (int w = 0; w < BLOCK / 64; ++w) { fsq += r_sq[w]; fpen += r_pen[w]; }
        out[0] = (float)(fsq * invN + fpen * invB);
    }
}

extern "C" void kernel_launch(void* const* d_in, const int* in_sizes, int n_in,
                              void* d_out, int out_size, void* d_ws, size_t ws_size,
                              hipStream_t stream) {
    const float* outs = (const float*)d_in[0];
    const float* tgts = (const float*)d_in[1];
    float* out = (float*)d_out;
    float2* partials = (float2*)d_ws;

    const long long n = (long long)in_sizes[0];        // B*3
    const long long n4 = n >> 2;
    const int nblocks = (int)((n4 + F4_PER_BLOCK - 1) / F4_PER_BLOCK); // 3072
    const double invN = 1.0 / (double)n;               // mse divisor = B*3
    const double invB = 3.0 / (double)n;               // penalty divisor = B

    // partials[0..nblocks) fully overwritten each launch -> no memset needed
    bcmse_partial<<<nblocks, BLOCK, 0, stream>>>(outs, tgts, n, partials);
    bcmse_reduce<<<1, BLOCK, 0, stream>>>(partials, nblocks, out, invN, invB);
}